// Round 1
// 283.873 us; speedup vs baseline: 1.1309x; 1.1309x over previous
//
#include <hip/hip_runtime.h>
#include <math.h>

#define BB 4
#define CC 64
#define OO 64
#define HH 128
#define WWD 128
#define HWP (HH*WWD)   // 16384

typedef short bf16x8 __attribute__((ext_vector_type(8)));
typedef float f32x4  __attribute__((ext_vector_type(4)));

__device__ __forceinline__ unsigned short bf16_rne(float f) {
    unsigned u = __float_as_uint(f);
    u += 0x7fffu + ((u >> 16) & 1u);
    return (unsigned short)(u >> 16);
}
__device__ __forceinline__ float bf16_tof(unsigned short h) {
    return __uint_as_float((unsigned)h << 16);
}

// ---------------------------------------------------------------------------
// Kernel 1: W[o][c][3][3] fp32 -> Whi/Wlo[k][o][c] bf16 (hi/lo split) for
// both layers. grid: 288 x 256 = 73728 = 2 * 64*64*9
// ---------------------------------------------------------------------------
__global__ __launch_bounds__(256) void wtrans_kernel(
    const float* __restrict__ W1, const float* __restrict__ W2,
    unsigned short* __restrict__ Wh1, unsigned short* __restrict__ Wl1,
    unsigned short* __restrict__ Wh2, unsigned short* __restrict__ Wl2)
{
    int idx = blockIdx.x * 256 + threadIdx.x;
    const int n = OO * CC * 9;           // 36864
    const float* src;
    unsigned short *dh, *dl;
    if (idx >= n) { src = W2; dh = Wh2; dl = Wl2; idx -= n; }
    else          { src = W1; dh = Wh1; dl = Wl1; }
    // dst index = (k*64 + o)*64 + c
    int c = idx & 63;
    int o = (idx >> 6) & 63;
    int k = idx >> 12;
    float w = src[(o * CC + c) * 9 + k];
    unsigned short hi = bf16_rne(w);
    unsigned short lo = bf16_rne(w - bf16_tof(hi));
    dh[idx] = hi;
    dl[idx] = lo;
}

// ---------------------------------------------------------------------------
// issue_tap<DY,DX>: compute bilinear coords for tap (DY,DX) and ISSUE the
// global gather loads into register arrays (no combine yet). For DY==0 the
// y-interpolation weight is exactly 0 (ys = fy), so only 2 loads/channel;
// center tap needs 1 load/channel. 25/36 of the generic load count.
// ---------------------------------------------------------------------------
template<int DY, int DX>
__device__ __forceinline__ void issue_tap(
    const float* __restrict__ xbase, int y, int xx0i, float fy, float fx,
    float rh, float rw,
    float (&v00)[16], float (&v01)[16], float (&v10)[16], float (&v11)[16],
    float& w00, float& w01, float& w10, float& w11)
{
    if (DY == 0 && DX == 0) {
        const float* c00 = xbase + y * WWD + xx0i;
#pragma unroll
        for (int i = 0; i < 16; ++i) v00[i] = c00[i * HWP];
    } else if (DY == 0) {
        float xs = fx + (float)DX * rw;
        float x0f = floorf(xs);
        float tx = xs - x0f;
        int ix0 = min(max((int)x0f, 0), WWD - 1);
        int ix1 = min(ix0 + 1, WWD - 1);
        w00 = 1.f - tx; w01 = tx;
        const float* c00 = xbase + y * WWD + ix0;
        const float* c01 = xbase + y * WWD + ix1;
#pragma unroll
        for (int i = 0; i < 16; ++i) { v00[i] = c00[i*HWP]; v01[i] = c01[i*HWP]; }
    } else if (DX == 0) {
        float ys = fy + (float)DY * rh;
        float y0f = floorf(ys);
        float ty = ys - y0f;
        int iy0 = min(max((int)y0f, 0), HH - 1);
        int iy1 = min(iy0 + 1, HH - 1);
        w00 = 1.f - ty; w10 = ty;
        const float* c00 = xbase + iy0 * WWD + xx0i;
        const float* c10 = xbase + iy1 * WWD + xx0i;
#pragma unroll
        for (int i = 0; i < 16; ++i) { v00[i] = c00[i*HWP]; v10[i] = c10[i*HWP]; }
    } else {
        float ys = fy + (float)DY * rh;
        float xs = fx + (float)DX * rw;
        float y0f = floorf(ys), x0f = floorf(xs);
        float ty = ys - y0f, tx = xs - x0f;
        int iy0 = min(max((int)y0f, 0), HH - 1);
        int iy1 = min(iy0 + 1, HH - 1);
        int ix0 = min(max((int)x0f, 0), WWD - 1);
        int ix1 = min(ix0 + 1, WWD - 1);
        w00 = (1.f - ty) * (1.f - tx);
        w01 = (1.f - ty) * tx;
        w10 = ty * (1.f - tx);
        w11 = ty * tx;
        const float* c00 = xbase + iy0 * WWD + ix0;
        const float* c01 = xbase + iy0 * WWD + ix1;
        const float* c10 = xbase + iy1 * WWD + ix0;
        const float* c11 = xbase + iy1 * WWD + ix1;
#pragma unroll
        for (int i = 0; i < 16; ++i) {
            v00[i] = c00[i*HWP]; v01[i] = c01[i*HWP];
            v10[i] = c10[i*HWP]; v11[i] = c11[i*HWP];
        }
    }
}

// combine loaded values -> bf16 hi/lo, write to LDS sample tile
template<int DY, int DX>
__device__ __forceinline__ void finish_tap(
    const float (&v00)[16], const float (&v01)[16],
    const float (&v10)[16], const float (&v11)[16],
    float w00, float w01, float w10, float w11,
    unsigned short* sh_dst, unsigned short* sl_dst)
{
    union { unsigned short h[16]; uint4 q[2]; } svh, svl;
#pragma unroll
    for (int i = 0; i < 16; ++i) {
        float s;
        if (DY == 0 && DX == 0)      s = v00[i];
        else if (DY == 0)            s = w00 * v00[i] + w01 * v01[i];
        else if (DX == 0)            s = w00 * v00[i] + w10 * v10[i];
        else s = w00 * v00[i] + w01 * v01[i] + w10 * v10[i] + w11 * v11[i];
        unsigned short hs = bf16_rne(s);
        svh.h[i] = hs;
        svl.h[i] = bf16_rne(s - bf16_tof(hs));
    }
    *(uint4*)sh_dst       = svh.q[0];
    *(uint4*)(sh_dst + 8) = svh.q[1];
    *(uint4*)sl_dst       = svl.q[0];
    *(uint4*)(sl_dst + 8) = svl.q[1];
}

// ---------------------------------------------------------------------------
// Kernel 2: fused offsets-conv + main arconv, software-pipelined taps.
// grid: 1024 blocks x 256 threads (4 waves). XCD-chunked block swizzle.
// Phase A: conv3x3(x, w_off)+sigmoid -> rf  (per-block, partial per c-quarter,
//          LDS reduce) -- replaces the separate offs_kernel dispatch.
// Tap loop (fully unrolled, compile-time dy/dx): issue tap k+1 gather loads
// and weight-stage loads BEFORE tap k's MFMA phase; combine + LDS write after
// the post-MFMA barrier. One tap of latency exposed (prologue) instead of 9.
// MFMA: 16x16x32 bf16, hi/lo 3-product compensation (fp32-accurate).
// Fragment layouts per m89/m120: A[m=lane&15][k=quad*8+j],
//   B[k=quad*8+j][n=lane&15], D: col=lane&15, row=quad*4+reg.
// mode 1: out = relu(acc + bias). mode 2: out = resid + acc + bias.
// ---------------------------------------------------------------------------
__global__ __launch_bounds__(256) void arconv_kernel(
    const float*          __restrict__ xin,   // [B,C,H,W]
    const unsigned short* __restrict__ Whi,   // [9][O][C] bf16 hi
    const unsigned short* __restrict__ Wlo,   // [9][O][C] bf16 lo
    const float*          __restrict__ bias,
    const float*          __restrict__ woff,  // [2][C][3][3]
    const float*          __restrict__ boff,  // [2]
    const int* __restrict__ lo_p, const int* __restrict__ hi_p,
    const float* __restrict__ resid,
    float* __restrict__ out, int mode)
{
    __shared__ unsigned short sWh[OO * 72];  // [o][c] padded, 9216 B each
    __shared__ unsigned short sWl[OO * 72];
    __shared__ unsigned short sSh[64 * 72];  // [p][c] padded
    __shared__ unsigned short sSl[64 * 72];
    __shared__ float srf[2][64];             // rf_h/2, rf_w/2 per pixel

    int t    = threadIdx.x;
    int bid  = blockIdx.x;
    // XCD-chunked swizzle: 1024 blocks, 8 XCDs, bid%8 -> XCD (round-robin).
    // Gives each XCD 128 consecutive tiles = 64 contiguous rows (~2.4 MB
    // working set, fits 4 MB L2).
    int blk  = ((bid & 7) << 7) | (bid >> 3);
    int b    = blk >> 8;
    int tile = blk & 255;
    int p0   = tile * 64;
    int y    = p0 >> 7;
    int xb   = p0 & 127;

    int lane = t & 63;
    int wv   = t >> 6;
    int pl   = lane;            // sampling pixel
    int cq   = wv;              // sampling c-quarter
    int nidx = lane & 15;
    int quad = lane >> 4;
    int xx0i = xb + pl;
    float fy = (float)y;
    float fx = (float)xx0i;

    const float* xbase = xin + (size_t)b * CC * HWP + (size_t)cq * 16 * HWP;

    // ---- phase A: fused offsets conv (aliases sWh/sSh as f32 scratch) ----
    {
        float* swA = (float*)sWh;   // 1152 f32 = 4608 B  (<= 9216)
        float* red = (float*)sSh;   // 512 f32 x2 = 4096 B... 2048 f32 = 8192 B
        for (int i = t; i < 2 * CC * 9; i += 256) swA[i] = woff[i];
        __syncthreads();
        float a0 = 0.f, a1 = 0.f;
        {
            const float* xc = xbase;
#pragma unroll 4
            for (int ci = 0; ci < 16; ++ci) {
                int c = cq * 16 + ci;
                const float* w0 = swA + c * 9;
                const float* w1 = swA + (CC + c) * 9;
#pragma unroll
                for (int ky = 0; ky < 3; ++ky) {
                    int yy = y + ky - 1;
                    bool yok = (yy >= 0) && (yy < HH);
#pragma unroll
                    for (int kx = 0; kx < 3; ++kx) {
                        int xx = xx0i + kx - 1;
                        float v = 0.f;
                        if (yok && xx >= 0 && xx < WWD) v = xc[yy * WWD + xx];
                        a0 = fmaf(v, w0[ky * 3 + kx], a0);
                        a1 = fmaf(v, w1[ky * 3 + kx], a1);
                    }
                }
                xc += HWP;
            }
        }
        red[cq * 64 + pl]       = a0;
        red[256 + cq * 64 + pl] = a1;
        __syncthreads();
        if (t < 64) {
            float flo = (float)lo_p[0];
            float fhi = (float)hi_p[0];
            float s0 = red[t] + red[64 + t] + red[128 + t] + red[192 + t] + boff[0];
            float s1 = red[256 + t] + red[320 + t] + red[384 + t] + red[448 + t] + boff[1];
            float g0 = 1.f / (1.f + expf(-s0));
            float g1 = 1.f / (1.f + expf(-s1));
            srf[0][t] = (flo + (fhi - flo) * g0) * 0.5f;
            srf[1][t] = (flo + (fhi - flo) * g1) * 0.5f;
        }
        __syncthreads();
    }
    float rh = srf[0][pl];
    float rw = srf[1][pl];

    f32x4 acc[4] = {};
    float v00[16], v01[16], v10[16], v11[16];
    float w00 = 0.f, w01 = 0.f, w10 = 0.f, w11 = 0.f;
    uint4 wh0, wh1, wl0, wl1;
    const unsigned short* wgh = Whi;   // advances 4096 shorts per tap
    const unsigned short* wgl = Wlo;

    unsigned short* shp = &sSh[pl * 72 + cq * 16];
    unsigned short* slp = &sSl[pl * 72 + cq * 16];

#define ISSUE_W() do { \
        const uint4* whs_ = (const uint4*)wgh; \
        const uint4* wls_ = (const uint4*)wgl; \
        wh0 = whs_[t * 2]; wh1 = whs_[t * 2 + 1]; \
        wl0 = wls_[t * 2]; wl1 = wls_[t * 2 + 1]; \
        wgh += OO * CC; wgl += OO * CC; \
    } while (0)

#define WRITE_W() do { \
        unsigned short* dh_ = &sWh[(t >> 2) * 72 + (t & 3) * 16]; \
        unsigned short* dl_ = &sWl[(t >> 2) * 72 + (t & 3) * 16]; \
        *(uint4*)dh_       = wh0; *(uint4*)(dh_ + 8) = wh1; \
        *(uint4*)dl_       = wl0; *(uint4*)(dl_ + 8) = wl1; \
    } while (0)

#define MFMA_TAP() do { \
        _Pragma("unroll") \
        for (int ks = 0; ks < 2; ++ks) { \
            int boff_ = (wv * 16 + nidx) * 72 + quad * 8 + ks * 32; \
            bf16x8 bh = *(const bf16x8*)&sSh[boff_]; \
            bf16x8 bl = *(const bf16x8*)&sSl[boff_]; \
            _Pragma("unroll") \
            for (int mt = 0; mt < 4; ++mt) { \
                int aoff_ = (mt * 16 + nidx) * 72 + quad * 8 + ks * 32; \
                bf16x8 ah = *(const bf16x8*)&sWh[aoff_]; \
                bf16x8 al = *(const bf16x8*)&sWl[aoff_]; \
                acc[mt] = __builtin_amdgcn_mfma_f32_16x16x32_bf16(ah, bh, acc[mt], 0, 0, 0); \
                acc[mt] = __builtin_amdgcn_mfma_f32_16x16x32_bf16(al, bh, acc[mt], 0, 0, 0); \
                acc[mt] = __builtin_amdgcn_mfma_f32_16x16x32_bf16(ah, bl, acc[mt], 0, 0, 0); \
            } \
        } \
    } while (0)

#define STEP(NDY, NDX) do { \
        ISSUE_W(); \
        issue_tap<NDY, NDX>(xbase, y, xx0i, fy, fx, rh, rw, \
                            v00, v01, v10, v11, w00, w01, w10, w11); \
        MFMA_TAP(); \
        __syncthreads(); \
        finish_tap<NDY, NDX>(v00, v01, v10, v11, w00, w01, w10, w11, shp, slp); \
        WRITE_W(); \
        __syncthreads(); \
    } while (0)

    // prologue: stage tap 0 (dy=-1, dx=-1); only tap with exposed latency
    ISSUE_W();
    issue_tap<-1, -1>(xbase, y, xx0i, fy, fx, rh, rw,
                      v00, v01, v10, v11, w00, w01, w10, w11);
    finish_tap<-1, -1>(v00, v01, v10, v11, w00, w01, w10, w11, shp, slp);
    WRITE_W();
    __syncthreads();

    STEP(-1,  0);   // mfma tap0, stage tap1
    STEP(-1,  1);
    STEP( 0, -1);
    STEP( 0,  0);
    STEP( 0,  1);
    STEP( 1, -1);
    STEP( 1,  0);
    STEP( 1,  1);
    MFMA_TAP();     // tap 8

#undef STEP
#undef MFMA_TAP
#undef WRITE_W
#undef ISSUE_W

    // epilogue: o = mt*16 + quad*4 + r, px = wv*16 + nidx
    int px = wv * 16 + nidx;
#pragma unroll
    for (int mt = 0; mt < 4; ++mt) {
#pragma unroll
        for (int r = 0; r < 4; ++r) {
            int o = mt * 16 + quad * 4 + r;
            float v = acc[mt][r] + bias[o];
            size_t idx = (size_t)(b * OO + o) * HWP + p0 + px;
            if (mode == 1) v = fmaxf(v, 0.f);
            else           v += resid[idx];
            out[idx] = v;
        }
    }
}

// ---------------------------------------------------------------------------
extern "C" void kernel_launch(void* const* d_in, const int* in_sizes, int n_in,
                              void* d_out, int out_size, void* d_ws, size_t ws_size,
                              hipStream_t stream) {
    const float* x      = (const float*)d_in[0];
    const float* w_off1 = (const float*)d_in[1];
    const float* b_off1 = (const float*)d_in[2];
    const float* W1     = (const float*)d_in[3];
    const float* b1     = (const float*)d_in[4];
    const float* w_off2 = (const float*)d_in[5];
    const float* b_off2 = (const float*)d_in[6];
    const float* W2     = (const float*)d_in[7];
    const float* b2     = (const float*)d_in[8];
    const int*   lo_p   = (const int*)d_in[10];
    const int*   hi_p   = (const int*)d_in[11];
    float* outp = (float*)d_out;

    float* wsf = (float*)d_ws;
    float* t1  = wsf;                               // B*C*HW f32
    unsigned short* Wh1 = (unsigned short*)(t1 + (size_t)BB * CC * HWP);
    unsigned short* Wl1 = Wh1 + OO * CC * 9;        // 36864 each
    unsigned short* Wh2 = Wl1 + OO * CC * 9;
    unsigned short* Wl2 = Wh2 + OO * CC * 9;

    // 1. transpose+split both weight tensors
    wtrans_kernel<<<288, 256, 0, stream>>>(W1, W2, Wh1, Wl1, Wh2, Wl2);

    // 2. layer 1: fused offsets + arconv + relu -> t1
    arconv_kernel<<<1024, 256, 0, stream>>>(x, Wh1, Wl1, b1, w_off1, b_off1,
                                            lo_p, hi_p, nullptr, t1, 1);

    // 3. layer 2: fused offsets + arconv + residual -> out
    arconv_kernel<<<1024, 256, 0, stream>>>(t1, Wh2, Wl2, b2, w_off2, b_off2,
                                            lo_p, hi_p, x, outp, 2);
}

// Round 2
// 245.997 us; speedup vs baseline: 1.3050x; 1.1540x over previous
//
#include <hip/hip_runtime.h>
#include <math.h>

#define BB 4
#define CC 64
#define OO 64
#define HH 128
#define WWD 128
#define HWP (HH*WWD)   // 16384

typedef short bf16x8 __attribute__((ext_vector_type(8)));
typedef float f32x4  __attribute__((ext_vector_type(4)));
typedef float f32x2  __attribute__((ext_vector_type(2)));

__device__ __forceinline__ unsigned short bf16_rne(float f) {
    unsigned u = __float_as_uint(f);
    u += 0x7fffu + ((u >> 16) & 1u);
    return (unsigned short)(u >> 16);
}
__device__ __forceinline__ float bf16_tof(unsigned short h) {
    return __uint_as_float((unsigned)h << 16);
}
// unaligned-8B-capable float2 load (align 4): emits global_load_dwordx2 on gfx950
__device__ __forceinline__ f32x2 ld2(const float* p) {
    f32x2 r; __builtin_memcpy(&r, p, 2 * sizeof(float)); return r;
}

// lgkmcnt-only barrier: drains LDS ops (WAR safety on shared tiles) but leaves
// global loads (vmcnt) in flight across the barrier — the m201/HK counted-vmcnt
// pattern. __syncthreads() would emit s_waitcnt vmcnt(0) and kill the pipeline.
#define BARRIER_NOVM() do { \
    __builtin_amdgcn_sched_barrier(0); \
    asm volatile("s_waitcnt lgkmcnt(0)"); \
    __builtin_amdgcn_s_barrier(); \
    __builtin_amdgcn_sched_barrier(0); \
} while (0)

// ---------------------------------------------------------------------------
// Kernel 1: W[o][c][3][3] fp32 -> Whi/Wlo[k][o][c] bf16 (hi/lo split) for
// both layers. grid: 288 x 256 = 73728 = 2 * 64*64*9
// ---------------------------------------------------------------------------
__global__ __launch_bounds__(256) void wtrans_kernel(
    const float* __restrict__ W1, const float* __restrict__ W2,
    unsigned short* __restrict__ Wh1, unsigned short* __restrict__ Wl1,
    unsigned short* __restrict__ Wh2, unsigned short* __restrict__ Wl2)
{
    int idx = blockIdx.x * 256 + threadIdx.x;
    const int n = OO * CC * 9;           // 36864
    const float* src;
    unsigned short *dh, *dl;
    if (idx >= n) { src = W2; dh = Wh2; dl = Wl2; idx -= n; }
    else          { src = W1; dh = Wh1; dl = Wl1; }
    // dst index = (k*64 + o)*64 + c
    int c = idx & 63;
    int o = (idx >> 6) & 63;
    int k = idx >> 12;
    float w = src[(o * CC + c) * 9 + k];
    unsigned short hi = bf16_rne(w);
    unsigned short lo = bf16_rne(w - bf16_tof(hi));
    dh[idx] = hi;
    dl[idx] = lo;
}

// ---------------------------------------------------------------------------
// issue_tap<DY,DX>: compute bilinear coords for tap (DY,DX) and ISSUE the
// gather loads into register arrays (raw, no combine). x-adjacent pairs
// (ix0, ix0+1) are fetched as one unaligned float2; the ix0==127 clamp is
// resolved in finish_tap via a select (xhi flag). Loads per channel:
// corner 2xf32x2, row-edge (DY==0) 1xf32x2, col-edge (DX==0) 2xf32,
// center 1xf32.
// ---------------------------------------------------------------------------
template<int DY, int DX>
__device__ __forceinline__ void issue_tap(
    const float* __restrict__ xbase, int y, int xx0i, float fy, float fx,
    float rh, float rw,
    float (&v00)[16], float (&v01)[16], float (&v10)[16], float (&v11)[16],
    float& w00, float& w01, float& w10, float& w11, bool& xhi)
{
    if (DY == 0 && DX == 0) {
        const float* c00 = xbase + y * WWD + xx0i;
#pragma unroll
        for (int i = 0; i < 16; ++i) v00[i] = c00[i * HWP];
    } else if (DY == 0) {
        float xs = fx + (float)DX * rw;
        float x0f = floorf(xs);
        float tx = xs - x0f;
        int ix0 = min(max((int)x0f, 0), WWD - 1);
        int ix0c = min(ix0, WWD - 2);
        xhi = (ix0 == WWD - 1);
        w00 = 1.f - tx; w01 = tx;
        const float* c00 = xbase + y * WWD + ix0c;
#pragma unroll
        for (int i = 0; i < 16; ++i) {
            f32x2 p = ld2(c00 + i * HWP);
            v00[i] = p.x; v01[i] = p.y;
        }
    } else if (DX == 0) {
        float ys = fy + (float)DY * rh;
        float y0f = floorf(ys);
        float ty = ys - y0f;
        int iy0 = min(max((int)y0f, 0), HH - 1);
        int iy1 = min(iy0 + 1, HH - 1);
        w00 = 1.f - ty; w10 = ty;
        const float* c00 = xbase + iy0 * WWD + xx0i;
        const float* c10 = xbase + iy1 * WWD + xx0i;
#pragma unroll
        for (int i = 0; i < 16; ++i) { v00[i] = c00[i*HWP]; v10[i] = c10[i*HWP]; }
    } else {
        float ys = fy + (float)DY * rh;
        float xs = fx + (float)DX * rw;
        float y0f = floorf(ys), x0f = floorf(xs);
        float ty = ys - y0f, tx = xs - x0f;
        int iy0 = min(max((int)y0f, 0), HH - 1);
        int iy1 = min(iy0 + 1, HH - 1);
        int ix0 = min(max((int)x0f, 0), WWD - 1);
        int ix0c = min(ix0, WWD - 2);
        xhi = (ix0 == WWD - 1);
        w00 = (1.f - ty) * (1.f - tx);
        w01 = (1.f - ty) * tx;
        w10 = ty * (1.f - tx);
        w11 = ty * tx;
        const float* c0 = xbase + iy0 * WWD + ix0c;
        const float* c1 = xbase + iy1 * WWD + ix0c;
#pragma unroll
        for (int i = 0; i < 16; ++i) {
            f32x2 pt = ld2(c0 + i * HWP);
            f32x2 pb = ld2(c1 + i * HWP);
            v00[i] = pt.x; v01[i] = pt.y;
            v10[i] = pb.x; v11[i] = pb.y;
        }
    }
}

// combine loaded values -> bf16 hi/lo, write to LDS sample tile
template<int DY, int DX>
__device__ __forceinline__ void finish_tap(
    const float (&v00)[16], const float (&v01)[16],
    const float (&v10)[16], const float (&v11)[16],
    float w00, float w01, float w10, float w11, bool xhi,
    unsigned short* sh_dst, unsigned short* sl_dst)
{
    union { unsigned short h[16]; uint4 q[2]; } svh, svl;
#pragma unroll
    for (int i = 0; i < 16; ++i) {
        float s;
        if (DY == 0 && DX == 0) {
            s = v00[i];
        } else if (DY == 0) {
            float a0 = xhi ? v01[i] : v00[i];
            s = w00 * a0 + w01 * v01[i];
        } else if (DX == 0) {
            s = w00 * v00[i] + w10 * v10[i];
        } else {
            float t0 = xhi ? v01[i] : v00[i];
            float b0 = xhi ? v11[i] : v10[i];
            s = w00 * t0 + w01 * v01[i] + w10 * b0 + w11 * v11[i];
        }
        unsigned short hs = bf16_rne(s);
        svh.h[i] = hs;
        svl.h[i] = bf16_rne(s - bf16_tof(hs));
    }
    *(uint4*)sh_dst       = svh.q[0];
    *(uint4*)(sh_dst + 8) = svh.q[1];
    *(uint4*)sl_dst       = svl.q[0];
    *(uint4*)(sl_dst + 8) = svl.q[1];
}

// ---------------------------------------------------------------------------
// Kernel 2: fused offsets-conv + main arconv, software-pipelined taps.
// grid: 1024 blocks x 256 threads (4 waves). XCD-chunked block swizzle.
// Phase A: conv3x3(x, w_off)+sigmoid -> rf  (per-block, partial per c-quarter,
//          LDS reduce) -- replaces a separate offs dispatch.
// Tap loop (fully unrolled, compile-time dy/dx): issue tap k+1 gather + weight
// loads BEFORE tap k's MFMA phase; barriers are lgkmcnt-only so those loads
// stay in flight across them (counted vmcnt inserted by compiler at use).
// MFMA: 16x16x32 bf16, hi/lo 3-product compensation (fp32-accurate).
// Fragment layouts per m89/m120: A[m=lane&15][k=quad*8+j],
//   B[k=quad*8+j][n=lane&15], D: col=lane&15, row=quad*4+reg.
// mode 1: out = relu(acc + bias). mode 2: out = resid + acc + bias.
// ---------------------------------------------------------------------------
__global__ __launch_bounds__(256) void arconv_kernel(
    const float*          __restrict__ xin,   // [B,C,H,W]
    const unsigned short* __restrict__ Whi,   // [9][O][C] bf16 hi
    const unsigned short* __restrict__ Wlo,   // [9][O][C] bf16 lo
    const float*          __restrict__ bias,
    const float*          __restrict__ woff,  // [2][C][3][3]
    const float*          __restrict__ boff,  // [2]
    const int* __restrict__ lo_p, const int* __restrict__ hi_p,
    const float* __restrict__ resid,
    float* __restrict__ out, int mode)
{
    __shared__ unsigned short sWh[OO * 72];  // [o][c] padded, 9216 B each
    __shared__ unsigned short sWl[OO * 72];
    __shared__ unsigned short sSh[64 * 72];  // [p][c] padded
    __shared__ unsigned short sSl[64 * 72];
    __shared__ float srf[2][64];             // rf_h/2, rf_w/2 per pixel

    int t    = threadIdx.x;
    int bid  = blockIdx.x;
    // XCD-chunked swizzle: 1024 blocks, 8 XCDs, bid%8 -> XCD (round-robin).
    // Each XCD gets 128 consecutive tiles = 64 contiguous rows (~2.4 MB
    // working set, fits 4 MB L2).  [R1: FETCH 123MB -> 9.6MB]
    int blk  = ((bid & 7) << 7) | (bid >> 3);
    int b    = blk >> 8;
    int tile = blk & 255;
    int p0   = tile * 64;
    int y    = p0 >> 7;
    int xb   = p0 & 127;

    int lane = t & 63;
    int wv   = t >> 6;
    int pl   = lane;            // sampling pixel
    int cq   = wv;              // sampling c-quarter
    int nidx = lane & 15;
    int quad = lane >> 4;
    int xx0i = xb + pl;
    float fy = (float)y;
    float fx = (float)xx0i;

    // wave-uniform channel-quarter base: readfirstlane makes it provably
    // uniform -> saddr-form global loads (SGPR base + 32b voffset) instead of
    // per-lane 64-bit VALU address chains on ~450 loads/thread.
    int cqoff = __builtin_amdgcn_readfirstlane(cq * 16 * HWP);
    const float* xbase = xin + (size_t)b * CC * HWP + cqoff;

    // ---- phase A: fused offsets conv (aliases sWh/sSh as f32 scratch) ----
    {
        float* swA = (float*)sWh;   // 1152 f32 = 4608 B  (<= 9216)
        float* red = (float*)sSh;   // 2048 f32 = 8192 B
        for (int i = t; i < 2 * CC * 9; i += 256) swA[i] = woff[i];
        __syncthreads();
        float a0 = 0.f, a1 = 0.f;
        {
            const float* xc = xbase;
#pragma unroll 4
            for (int ci = 0; ci < 16; ++ci) {
                int c = cq * 16 + ci;
                const float* w0 = swA + c * 9;
                const float* w1 = swA + (CC + c) * 9;
#pragma unroll
                for (int ky = 0; ky < 3; ++ky) {
                    int yy = y + ky - 1;
                    bool yok = (yy >= 0) && (yy < HH);
#pragma unroll
                    for (int kx = 0; kx < 3; ++kx) {
                        int xx = xx0i + kx - 1;
                        float v = 0.f;
                        if (yok && xx >= 0 && xx < WWD) v = xc[yy * WWD + xx];
                        a0 = fmaf(v, w0[ky * 3 + kx], a0);
                        a1 = fmaf(v, w1[ky * 3 + kx], a1);
                    }
                }
                xc += HWP;
            }
        }
        red[cq * 64 + pl]       = a0;
        red[256 + cq * 64 + pl] = a1;
        __syncthreads();
        if (t < 64) {
            float flo = (float)lo_p[0];
            float fhi = (float)hi_p[0];
            float s0 = red[t] + red[64 + t] + red[128 + t] + red[192 + t] + boff[0];
            float s1 = red[256 + t] + red[320 + t] + red[384 + t] + red[448 + t] + boff[1];
            float g0 = 1.f / (1.f + expf(-s0));
            float g1 = 1.f / (1.f + expf(-s1));
            srf[0][t] = (flo + (fhi - flo) * g0) * 0.5f;
            srf[1][t] = (flo + (fhi - flo) * g1) * 0.5f;
        }
        __syncthreads();
    }
    float rh = srf[0][pl];
    float rw = srf[1][pl];

    f32x4 acc[4] = {};
    float v00[16], v01[16], v10[16], v11[16];
    float w00 = 0.f, w01 = 0.f, w10 = 0.f, w11 = 0.f;
    bool xhi = false;
    uint4 wh0, wh1, wl0, wl1;
    const unsigned short* wgh = Whi;   // advances 4096 shorts per tap
    const unsigned short* wgl = Wlo;

    unsigned short* shp = &sSh[pl * 72 + cq * 16];
    unsigned short* slp = &sSl[pl * 72 + cq * 16];

#define ISSUE_W() do { \
        const uint4* whs_ = (const uint4*)wgh; \
        const uint4* wls_ = (const uint4*)wgl; \
        wh0 = whs_[t * 2]; wh1 = whs_[t * 2 + 1]; \
        wl0 = wls_[t * 2]; wl1 = wls_[t * 2 + 1]; \
        wgh += OO * CC; wgl += OO * CC; \
    } while (0)

#define WRITE_W() do { \
        unsigned short* dh_ = &sWh[(t >> 2) * 72 + (t & 3) * 16]; \
        unsigned short* dl_ = &sWl[(t >> 2) * 72 + (t & 3) * 16]; \
        *(uint4*)dh_       = wh0; *(uint4*)(dh_ + 8) = wh1; \
        *(uint4*)dl_       = wl0; *(uint4*)(dl_ + 8) = wl1; \
    } while (0)

#define MFMA_TAP() do { \
        _Pragma("unroll") \
        for (int ks = 0; ks < 2; ++ks) { \
            int boff_ = (wv * 16 + nidx) * 72 + quad * 8 + ks * 32; \
            bf16x8 bh = *(const bf16x8*)&sSh[boff_]; \
            bf16x8 bl = *(const bf16x8*)&sSl[boff_]; \
            _Pragma("unroll") \
            for (int mt = 0; mt < 4; ++mt) { \
                int aoff_ = (mt * 16 + nidx) * 72 + quad * 8 + ks * 32; \
                bf16x8 ah = *(const bf16x8*)&sWh[aoff_]; \
                bf16x8 al = *(const bf16x8*)&sWl[aoff_]; \
                acc[mt] = __builtin_amdgcn_mfma_f32_16x16x32_bf16(ah, bh, acc[mt], 0, 0, 0); \
                acc[mt] = __builtin_amdgcn_mfma_f32_16x16x32_bf16(al, bh, acc[mt], 0, 0, 0); \
                acc[mt] = __builtin_amdgcn_mfma_f32_16x16x32_bf16(ah, bl, acc[mt], 0, 0, 0); \
            } \
        } \
    } while (0)

#define STEP(NDY, NDX) do { \
        ISSUE_W(); \
        issue_tap<NDY, NDX>(xbase, y, xx0i, fy, fx, rh, rw, \
                            v00, v01, v10, v11, w00, w01, w10, w11, xhi); \
        MFMA_TAP(); \
        BARRIER_NOVM(); \
        finish_tap<NDY, NDX>(v00, v01, v10, v11, w00, w01, w10, w11, xhi, shp, slp); \
        WRITE_W(); \
        BARRIER_NOVM(); \
    } while (0)

    // prologue: stage tap 0 (dy=-1, dx=-1); only tap with exposed latency
    ISSUE_W();
    issue_tap<-1, -1>(xbase, y, xx0i, fy, fx, rh, rw,
                      v00, v01, v10, v11, w00, w01, w10, w11, xhi);
    finish_tap<-1, -1>(v00, v01, v10, v11, w00, w01, w10, w11, xhi, shp, slp);
    WRITE_W();
    __syncthreads();

    STEP(-1,  0);   // mfma tap0, stage tap1
    STEP(-1,  1);
    STEP( 0, -1);
    STEP( 0,  0);
    STEP( 0,  1);
    STEP( 1, -1);
    STEP( 1,  0);
    STEP( 1,  1);
    MFMA_TAP();     // tap 8

#undef STEP
#undef MFMA_TAP
#undef WRITE_W
#undef ISSUE_W

    // epilogue: o = mt*16 + quad*4 + r, px = wv*16 + nidx
    int px = wv * 16 + nidx;
#pragma unroll
    for (int mt = 0; mt < 4; ++mt) {
#pragma unroll
        for (int r = 0; r < 4; ++r) {
            int o = mt * 16 + quad * 4 + r;
            float v = acc[mt][r] + bias[o];
            size_t idx = (size_t)(b * OO + o) * HWP + p0 + px;
            if (mode == 1) v = fmaxf(v, 0.f);
            else           v += resid[idx];
            out[idx] = v;
        }
    }
}

// ---------------------------------------------------------------------------
extern "C" void kernel_launch(void* const* d_in, const int* in_sizes, int n_in,
                              void* d_out, int out_size, void* d_ws, size_t ws_size,
                              hipStream_t stream) {
    const float* x      = (const float*)d_in[0];
    const float* w_off1 = (const float*)d_in[1];
    const float* b_off1 = (const float*)d_in[2];
    const float* W1     = (const float*)d_in[3];
    const float* b1     = (const float*)d_in[4];
    const float* w_off2 = (const float*)d_in[5];
    const float* b_off2 = (const float*)d_in[6];
    const float* W2     = (const float*)d_in[7];
    const float* b2     = (const float*)d_in[8];
    const int*   lo_p   = (const int*)d_in[10];
    const int*   hi_p   = (const int*)d_in[11];
    float* outp = (float*)d_out;

    float* wsf = (float*)d_ws;
    float* t1  = wsf;                               // B*C*HW f32
    unsigned short* Wh1 = (unsigned short*)(t1 + (size_t)BB * CC * HWP);
    unsigned short* Wl1 = Wh1 + OO * CC * 9;        // 36864 each
    unsigned short* Wh2 = Wl1 + OO * CC * 9;
    unsigned short* Wl2 = Wh2 + OO * CC * 9;

    // 1. transpose+split both weight tensors
    wtrans_kernel<<<288, 256, 0, stream>>>(W1, W2, Wh1, Wl1, Wh2, Wl2);

    // 2. layer 1: fused offsets + arconv + relu -> t1
    arconv_kernel<<<1024, 256, 0, stream>>>(x, Wh1, Wl1, b1, w_off1, b_off1,
                                            lo_p, hi_p, nullptr, t1, 1);

    // 3. layer 2: fused offsets + arconv + residual -> out
    arconv_kernel<<<1024, 256, 0, stream>>>(t1, Wh2, Wl2, b2, w_off2, b_off2,
                                            lo_p, hi_p, x, outp, 2);
}